// Round 8
// baseline (266.706 us; speedup 1.0000x reference)
//
#include <hip/hip_runtime.h>
#include <hip/hip_bf16.h>
#include <math.h>

// VOCAB=50000, EMBED=256, MAXLEN=512, UNITS=32, F1=16, BATCH=512.
#define TT 512
#define BB 512
#define EE 256
#define UU 32
#define FF1 16
#define WIN 64
#define NWIN (TT / WIN)   // 8

__device__ __forceinline__ void fma4(float4& a, float s, const float4& v) {
    a.x = fmaf(s, v.x, a.x); a.y = fmaf(s, v.y, a.y);
    a.z = fmaf(s, v.z, a.z); a.w = fmaf(s, v.w, a.w);
}

// tanh(x) = 1 - 2/(e^{2x}+1), branch-free (exp2+rcp HW approx).
__device__ __forceinline__ float fast_tanh(float x) {
    float e = __builtin_amdgcn_exp2f(x * 2.8853900817779268f);  // e^{2x}
    float r = __builtin_amdgcn_rcpf(e + 1.0f);
    return fmaf(-2.0f, r, 1.0f);
}

__device__ __forceinline__ float rdlane(float v, int lane) {
    return __int_as_float(__builtin_amdgcn_readlane(__float_as_int(v), lane));
}

// ---------------------------------------------------------------------------
// Fused RNN: one block (3 waves) per batch row.
//   wave 0 : sequential scan h_t = tanh(x_t + h @ Wh)  (round-6 readlane body
//            — bpermute regressed in round 7, reverted)
//   waves 1-2: producer GEMV — x_t = emb[tok_t] @ Wx + bias for the NEXT
//            64-step window into double-buffered LDS (8 KB per window).
// Producers (~11k cyc issue/window) hide under the scan window (~22.5k cyc);
// __syncthreads per window. Kills the proj kernel, the 6.4 MB P round-trip,
// the 64-instr gather phase, and one kernel launch.
// ---------------------------------------------------------------------------
__global__ __launch_bounds__(192) void rnn_fused(
    const int* __restrict__ tokens, const float* __restrict__ emb,
    const float* __restrict__ Wx, const float* __restrict__ bias,
    const float* __restrict__ Wh,
    const float* __restrict__ W1, const float* __restrict__ b1,
    const float* __restrict__ W2, const float* __restrict__ b2,
    float* __restrict__ out)
{
    __shared__ float sWx[EE * UU];        // 32 KB, staged once
    __shared__ float buf[2][WIN * UU];    // 2 x 8 KB x-windows

    const int tid = threadIdx.x;
    const int L   = tid & 63;
    const int wv  = tid >> 6;             // 0 = scan wave, 1..2 = producers
    const int b   = blockIdx.x;
    const int* trow = tokens + b * TT;

    // ---- stage Wx into LDS (all 192 threads) ----
    {
        float4* dst = (float4*)sWx;
        const float4* src = (const float4*)Wx;
        for (int i = tid; i < EE * UU / 4; i += 192) dst[i] = src[i];
    }

    // scan-wave constants (loaded by all waves; avoids divergence, harmless)
    const int u = L & 31;
    float wh[UU];
    #pragma unroll
    for (int k = 0; k < UU; ++k) wh[k] = Wh[k * UU + u];

    // producer constants
    const int ug = L & 7, rg = L >> 3;
    const float4 bq = ((const float4*)bias)[ug];
    const float4* sw4 = (const float4*)sWx + ug;   // Wx row k -> sw4[k*8]

    __syncthreads();   // sWx resident

    // producer: fill window w (rows w*64 .. w*64+63); this wave does 32 rows,
    // 2 passes x (2 rows/lane, 8 rg-groups x 8 ug-quads) — round-7 GEMV body
    // with Wx from LDS (broadcast ds_read_b128, conflict-free).
    auto produce = [&](int w) {
        float* dstbuf = buf[w & 1];
        const int t0 = w * WIN;
        #pragma unroll 1
        for (int pass = 0; pass < 2; ++pass) {
            const int r0 = t0 + (wv - 1) * 32 + pass * 16 + rg * 2;
            const int tok0 = trow[r0], tok1 = trow[r0 + 1];
            const float4* xp0 = (const float4*)(emb + (size_t)tok0 * EE);
            const float4* xp1 = (const float4*)(emb + (size_t)tok1 * EE);

            float4 acc0 = make_float4(0.f, 0.f, 0.f, 0.f);
            float4 acc1 = make_float4(0.f, 0.f, 0.f, 0.f);
            float4 xA0 = xp0[0], xA1 = xp1[0], xB0, xB1, wA[4], wB[4];
            #pragma unroll
            for (int kk = 0; kk < 4; ++kk) wA[kk] = sw4[kk * 8];

            for (int k4 = 0; k4 < 64; k4 += 2) {
                // prefetch odd iter
                xB0 = xp0[k4 + 1]; xB1 = xp1[k4 + 1];
                #pragma unroll
                for (int kk = 0; kk < 4; ++kk) wB[kk] = sw4[(4 * (k4 + 1) + kk) * 8];
                // compute even iter
                fma4(acc0, xA0.x, wA[0]); fma4(acc0, xA0.y, wA[1]);
                fma4(acc0, xA0.z, wA[2]); fma4(acc0, xA0.w, wA[3]);
                fma4(acc1, xA1.x, wA[0]); fma4(acc1, xA1.y, wA[1]);
                fma4(acc1, xA1.z, wA[2]); fma4(acc1, xA1.w, wA[3]);
                // prefetch next even iter (wraps on last pass — harmless)
                const int kn = (k4 + 2) & 63;
                xA0 = xp0[kn]; xA1 = xp1[kn];
                #pragma unroll
                for (int kk = 0; kk < 4; ++kk) wA[kk] = sw4[(4 * kn + kk) * 8];
                // compute odd iter
                fma4(acc0, xB0.x, wB[0]); fma4(acc0, xB0.y, wB[1]);
                fma4(acc0, xB0.z, wB[2]); fma4(acc0, xB0.w, wB[3]);
                fma4(acc1, xB1.x, wB[0]); fma4(acc1, xB1.y, wB[1]);
                fma4(acc1, xB1.z, wB[2]); fma4(acc1, xB1.w, wB[3]);
            }
            acc0.x += bq.x; acc0.y += bq.y; acc0.z += bq.z; acc0.w += bq.w;
            acc1.x += bq.x; acc1.y += bq.y; acc1.z += bq.z; acc1.w += bq.w;
            ((float4*)(dstbuf + (r0 - t0) * UU))[ug]     = acc0;
            ((float4*)(dstbuf + (r0 + 1 - t0) * UU))[ug] = acc1;
        }
    };

    if (wv > 0) produce(0);
    __syncthreads();   // window 0 ready

    float h = 0.f;     // h[u], replicated across both 32-lane halves of wave 0

    for (int w = 0; w < NWIN; ++w) {
        if (wv == 0) {
            const float* cur = buf[w & 1];
            float xv = cur[u];                       // first x of window
            #pragma unroll 4
            for (int j = 0; j < WIN; ++j) {
                // prefetch next x (wraps at window end: discarded)
                float xn = cur[((j + 1) & (WIN - 1)) * UU + u];

                float a0 = xv, a1 = 0.f, a2 = 0.f, a3 = 0.f;
                #pragma unroll
                for (int k = 0; k < UU; k += 4) {
                    float h0 = rdlane(h, k);
                    float h1 = rdlane(h, k + 1);
                    float h2 = rdlane(h, k + 2);
                    float h3 = rdlane(h, k + 3);
                    a0 = fmaf(h0, wh[k],     a0);
                    a1 = fmaf(h1, wh[k + 1], a1);
                    a2 = fmaf(h2, wh[k + 2], a2);
                    a3 = fmaf(h3, wh[k + 3], a3);
                }
                h = fast_tanh((a0 + a1) + (a2 + a3));
                xv = xn;
            }
        } else if (w < NWIN - 1) {
            produce(w + 1);
        }
        __syncthreads();   // window w fully consumed, window w+1 ready
    }

    // ---- fused heads (wave 0; readlane-only) ----
    if (wv == 0) {
        const int jh = L & 15;
        float s = b1[jh];
        #pragma unroll
        for (int k = 0; k < UU; ++k) {
            float hk = rdlane(h, k);
            s = fmaf(hk, W1[k * FF1 + jh], s);
        }
        float z = b2[0];
        #pragma unroll
        for (int jj = 0; jj < FF1; ++jj) {
            float yj = rdlane(s, jj);
            z = fmaf(yj, W2[jj], z);
        }
        if (tid == 0) {
            float e = __builtin_amdgcn_exp2f(-z * 1.4426950408889634f);
            out[b] = __builtin_amdgcn_rcpf(1.0f + e);
        }
    }
}

// ---------------------------------------------------------------------------
extern "C" void kernel_launch(void* const* d_in, const int* in_sizes, int n_in,
                              void* d_out, int out_size, void* d_ws, size_t ws_size,
                              hipStream_t stream) {
    const int*   tokens = (const int*)  d_in[0];
    const float* emb    = (const float*)d_in[1];
    const float* Wx     = (const float*)d_in[2];
    const float* Wh     = (const float*)d_in[3];
    const float* bias   = (const float*)d_in[4];
    const float* W1     = (const float*)d_in[5];
    const float* b1     = (const float*)d_in[6];
    const float* W2     = (const float*)d_in[7];
    const float* b2     = (const float*)d_in[8];
    float* out = (float*)d_out;

    // ONE kernel: 512 blocks x 192 threads (1 scan wave + 2 producer waves)
    rnn_fused<<<dim3(BB), dim3(192), 0, stream>>>(
        tokens, emb, Wx, bias, Wh, W1, b1, W2, b2, out);
}

// Round 9
// 217.424 us; speedup vs baseline: 1.2267x; 1.2267x over previous
//
#include <hip/hip_runtime.h>
#include <hip/hip_bf16.h>
#include <math.h>

// VOCAB=50000, EMBED=256, MAXLEN=512, UNITS=32, F1=16, BATCH=512.
#define TT 512
#define BB 512
#define EE 256
#define UU 32
#define FF1 16

// tanh(x) = 1 - 2/(e^{2x}+1), branch-free (exp2+rcp HW approx).
__device__ __forceinline__ float fast_tanh(float x) {
    float e = __builtin_amdgcn_exp2f(x * 2.8853900817779268f);  // e^{2x}
    float r = __builtin_amdgcn_rcpf(e + 1.0f);
    return fmaf(-2.0f, r, 1.0f);
}

__device__ __forceinline__ float rdlane(float v, int lane) {
    return __int_as_float(__builtin_amdgcn_readlane(__float_as_int(v), lane));
}

// ---------------------------------------------------------------------------
// Kernel A: P[r][u] = emb[r] @ Wx[:,u] + bias[u] — ONE ROW PER LANE.
// Key property: Wx row addresses are WAVE-UNIFORM -> compiler emits
// s_load (K$, scalar pipe, parallel to VALU): zero VMEM instructions spent
// on weights. x is read in 64-B chunks (4 x float4 per 16-k stage, full
// cache-line utilization) with a 2-stage ring: slack per stage = 32 fmac
// x 16 k = 1024 cyc >> HBM latency. acc[32] lives in VGPRs; stores are one
// full 128-B line per lane. Accumulation order identical to round 6
// (k ascending per u) -> bit-identical P.
// ---------------------------------------------------------------------------
__global__ __launch_bounds__(64) void proj_rows(
    const float* __restrict__ emb, const float* __restrict__ Wx,
    const float* __restrict__ bias, float* __restrict__ P, int nrows)
{
    int r = blockIdx.x * 64 + threadIdx.x;
    if (r >= nrows) r = nrows - 1;      // tail lanes duplicate row nrows-1
                                        // (identical bytes, benign race)
    const float4* xp = (const float4*)(emb + (size_t)r * EE);

    float acc[UU];
    #pragma unroll
    for (int u = 0; u < UU; ++u) acc[u] = 0.f;

    // one 16-k stage: acc[u] += sum over 16 k's (k ascending, as round 6)
    auto stage = [&](const float4* xq, int kbase) {
        #pragma unroll
        for (int i = 0; i < 4; ++i) {
            const float xc[4] = {xq[i].x, xq[i].y, xq[i].z, xq[i].w};
            #pragma unroll
            for (int c = 0; c < 4; ++c) {
                const float* w = Wx + (size_t)(kbase + i * 4 + c) * UU;
                #pragma unroll
                for (int u = 0; u < UU; ++u)
                    acc[u] = fmaf(xc[c], w[u], acc[u]);   // w[u]: SGPR operand
            }
        }
    };

    float4 xA[4], xB[4];
    #pragma unroll
    for (int i = 0; i < 4; ++i) xA[i] = xp[i];            // stage 0

    #pragma unroll 1
    for (int m = 0; m < 16; m += 2) {   // 16 stages of 16 k's
        #pragma unroll
        for (int i = 0; i < 4; ++i) xB[i] = xp[(m + 1) * 4 + i];
        stage(xA, m * 16);
        #pragma unroll
        for (int i = 0; i < 4; ++i) xA[i] = xp[((m + 2) & 15) * 4 + i];
        stage(xB, (m + 1) * 16);
    }

    float4* o = (float4*)(P + (size_t)r * UU);            // own 128-B line
    #pragma unroll
    for (int j4 = 0; j4 < 8; ++j4) {
        float4 v;
        v.x = acc[j4 * 4 + 0] + bias[j4 * 4 + 0];
        v.y = acc[j4 * 4 + 1] + bias[j4 * 4 + 1];
        v.z = acc[j4 * 4 + 2] + bias[j4 * 4 + 2];
        v.w = acc[j4 * 4 + 3] + bias[j4 * 4 + 3];
        o[j4] = v;
    }
}

// ---------------------------------------------------------------------------
// Kernel B (round-6 verbatim — best known: 75 us):
// h_t = tanh(x_t + h_{t-1} @ Wh); fused heads + sigmoid.
// One batch row per 64-lane wave; x-stream (64 KB) staged in LDS upfront
// via gathered global_load_lds width=16. Scan loop: zero global accesses,
// interleaved readlane/FMA, fast tanh.
// ---------------------------------------------------------------------------
__global__ __launch_bounds__(64) void scan_heads(
    const int* __restrict__ tokens, const float* __restrict__ P,
    const float* __restrict__ Wh,
    const float* __restrict__ W1, const float* __restrict__ b1,
    const float* __restrict__ W2, const float* __restrict__ b2,
    float* __restrict__ out)
{
    __shared__ float xs[TT * UU];      // 512 rows x 128 B = 64 KB

    const int L = threadIdx.x;
    const int u = L & 31;
    const int b = blockIdx.x;
    const int* trow = tokens + b * TT;

    // wh[k] = Wh[k][u] : this lane's column of the recurrent matrix
    float wh[UU];
    #pragma unroll
    for (int k = 0; k < UU; ++k) wh[k] = Wh[k * UU + u];

    // ---- gather phase: 64 global_load_lds instrs, 8 tokens each ----
    const int sub = L >> 3;            // token-within-group
    const int q   = L & 7;             // 16-B chunk within the 128-B row
    for (int c = 0; c < 8; ++c) {
        int tk8[8];
        #pragma unroll
        for (int i = 0; i < 8; ++i)
            tk8[i] = trow[c * 64 + i * 8 + sub];
        #pragma unroll
        for (int i = 0; i < 8; ++i) {
            const float* src = P + (size_t)tk8[i] * UU + q * 4;
            float* dst = xs + (c * 64 + i * 8) * UU;    // wave-uniform base
            __builtin_amdgcn_global_load_lds(
                (const __attribute__((address_space(1))) void*)src,
                (__attribute__((address_space(3))) void*)dst, 16, 0, 0);
        }
    }
    __syncthreads();   // drains vmcnt: all LDS rows resident

    // ---- scan: pure LDS + VALU ----
    float xr[4];
    #pragma unroll
    for (int j = 0; j < 4; ++j) xr[j] = xs[j * UU + u];

    float h = 0.f;

    for (int t = 0; t < TT; t += 4) {
        #pragma unroll
        for (int j = 0; j < 4; ++j) {
            float xn = xs[((t + 4 + j) & (TT - 1)) * UU + u];  // prefetch

            float a0 = xr[j], a1 = 0.f, a2 = 0.f, a3 = 0.f;
            #pragma unroll
            for (int k = 0; k < UU; k += 4) {
                float h0 = rdlane(h, k);
                float h1 = rdlane(h, k + 1);
                float h2 = rdlane(h, k + 2);
                float h3 = rdlane(h, k + 3);
                a0 = fmaf(h0, wh[k],     a0);
                a1 = fmaf(h1, wh[k + 1], a1);
                a2 = fmaf(h2, wh[k + 2], a2);
                a3 = fmaf(h3, wh[k + 3], a3);
            }
            h = fast_tanh((a0 + a1) + (a2 + a3));
            xr[j] = xn;
        }
    }

    // ---- fused heads (once; readlane-only) ----
    const int j = threadIdx.x & 15;
    float s = b1[j];
    #pragma unroll
    for (int k = 0; k < UU; ++k) {
        float hk = rdlane(h, k);
        s = fmaf(hk, W1[k * FF1 + j], s);
    }
    float z = b2[0];
    #pragma unroll
    for (int jj = 0; jj < FF1; ++jj) {
        float yj = rdlane(s, jj);
        z = fmaf(yj, W2[jj], z);
    }
    if (threadIdx.x == 0) {
        float e = __builtin_amdgcn_exp2f(-z * 1.4426950408889634f); // e^{-z}
        out[b] = __builtin_amdgcn_rcpf(1.0f + e);
    }
}

// ---------------------------------------------------------------------------
extern "C" void kernel_launch(void* const* d_in, const int* in_sizes, int n_in,
                              void* d_out, int out_size, void* d_ws, size_t ws_size,
                              hipStream_t stream) {
    const int*   tokens = (const int*)  d_in[0];
    const float* emb    = (const float*)d_in[1];
    const float* Wx     = (const float*)d_in[2];
    const float* Wh     = (const float*)d_in[3];
    const float* bias   = (const float*)d_in[4];
    const float* W1     = (const float*)d_in[5];
    const float* b1     = (const float*)d_in[6];
    const float* W2     = (const float*)d_in[7];
    const float* b2     = (const float*)d_in[8];
    float* out = (float*)d_out;

    const int vocab = in_sizes[1] / EE;        // 50000
    float* P = (float*)d_ws;                   // vocab*32*4 = 6.4 MB

    // A: 1 row per lane -> 782 blocks x 64 threads
    proj_rows<<<dim3((vocab + 63) / 64), dim3(64), 0, stream>>>(
        emb, Wx, bias, P, vocab);

    // B: 1 batch row per wave -> 512 blocks x 64 threads (2 blocks/CU)
    scan_heads<<<dim3(BB), dim3(64), 0, stream>>>(
        tokens, P, Wh, W1, b1, W2, b2, out);
}

// Round 10
// 186.705 us; speedup vs baseline: 1.4285x; 1.1645x over previous
//
#include <hip/hip_runtime.h>
#include <hip/hip_bf16.h>
#include <math.h>

// VOCAB=50000, EMBED=256, MAXLEN=512, UNITS=32, F1=16, BATCH=512.
#define TT 512
#define BB 512
#define EE 256
#define UU 32
#define FF1 16
#define NWAVE 2048            // proj waves: 8/CU, 2/SIMD

// tanh(x) = 1 - 2/(e^{2x}+1), branch-free (exp2+rcp HW approx).
__device__ __forceinline__ float fast_tanh(float x) {
    float e = __builtin_amdgcn_exp2f(x * 2.8853900817779268f);  // e^{2x}
    float r = __builtin_amdgcn_rcpf(e + 1.0f);
    return fmaf(-2.0f, r, 1.0f);
}

__device__ __forceinline__ float rdlane(float v, int lane) {
    return __int_as_float(__builtin_amdgcn_readlane(__float_as_int(v), lane));
}

// v += value from lane (i - N) within the 16-lane DPP row (0 past row edge).
// VALU-pipe cross-lane: rocPRIM reduction pattern, ctrl = 0x110|N (row_shr:N).
#define DPP_ADD(v, ctrl)                                                    \
    (v) += __int_as_float(__builtin_amdgcn_update_dpp(                      \
        0, __float_as_int(v), (ctrl), 0xf, 0xf, true))

// ---------------------------------------------------------------------------
// Kernel A: P[r][u] = emb[r] @ Wx[:,u] + bias[u] — DPP-reduce GEMV.
// Lane (g=L>>4, c=L&15): u-octet g, k strided (k = c+16*kk).
//  * w preload COALESCED (fixed kk -> 64 lanes tile contiguous 2 KB),
//    held in 128 VGPRs: zero per-row weight traffic on any pipe.
//  * x: 16 dword loads/row, each instr spans 64 B (1-2 lines); 2-row
//    ping-pong prefetch.
//  * reduce over c: 4 DPP row_shr stages per u (VALU pipe, no LDS);
//    lane c==15 stores its u-octet (32 B).
// ~280 cyc/row; 2048 waves x ~25 rows; memory floor ~6-8 us.
// ---------------------------------------------------------------------------
__global__ __launch_bounds__(64) void proj_dpp(
    const float* __restrict__ emb, const float* __restrict__ Wx,
    const float* __restrict__ bias, float* __restrict__ P, int nrows)
{
    const int L = threadIdx.x;
    const int g = L >> 4;              // u-octet 0..3
    const int c = L & 15;              // k-lane 0..15
    const int wv = blockIdx.x;         // 0..NWAVE-1

    // ---- one-time coalesced w preload: w[kk][uu] = Wx[c+16*kk][g*8+uu]
    float w[16][8];
    #pragma unroll
    for (int kk = 0; kk < 16; ++kk) {
        const float4* src = (const float4*)(Wx + (size_t)(kk * 16 + c) * UU + g * 8);
        float4 a = src[0], b = src[1];
        w[kk][0] = a.x; w[kk][1] = a.y; w[kk][2] = a.z; w[kk][3] = a.w;
        w[kk][4] = b.x; w[kk][5] = b.y; w[kk][6] = b.z; w[kk][7] = b.w;
    }
    float bs[8];
    #pragma unroll
    for (int uu = 0; uu < 8; ++uu) bs[uu] = bias[g * 8 + uu];

    // rows handled by this wave: r = wv + NWAVE*i
    auto rowptr = [&](int i) {
        int r = wv + NWAVE * i;
        if (r >= nrows) r = nrows - 1;             // clamped dummy
        return emb + (size_t)r * EE;
    };

    float xA[16], xB[16];
    {
        const float* rp = rowptr(0);
        #pragma unroll
        for (int kk = 0; kk < 16; ++kk) xA[kk] = rp[kk * 16 + c];
    }

    const int NI = (nrows - 1 - wv) / NWAVE + 1;   // #valid rows (wv < nrows)

    for (int i = 0; i < NI; ++i) {
        // prefetch next row (clamped at tail)
        {
            const float* rp = rowptr(i + 1 < NI ? i + 1 : i);
            #pragma unroll
            for (int kk = 0; kk < 16; ++kk) xB[kk] = rp[kk * 16 + c];
        }

        // partials for this lane's 16 k's x 8 u's
        float p[8];
        #pragma unroll
        for (int uu = 0; uu < 8; ++uu) p[uu] = 0.f;
        #pragma unroll
        for (int kk = 0; kk < 16; ++kk) {
            const float xk = xA[kk];
            #pragma unroll
            for (int uu = 0; uu < 8; ++uu)
                p[uu] = fmaf(xk, w[kk][uu], p[uu]);
        }

        // reduce over the 16 c-lanes (DPP row-of-16); lane c==15 holds sums
        #pragma unroll
        for (int uu = 0; uu < 8; ++uu) {
            DPP_ADD(p[uu], 0x111);   // row_shr:1
            DPP_ADD(p[uu], 0x112);   // row_shr:2
            DPP_ADD(p[uu], 0x114);   // row_shr:4
            DPP_ADD(p[uu], 0x118);   // row_shr:8
        }

        if (c == 15) {
            const int r = wv + NWAVE * i;
            float4 o0, o1;
            o0.x = p[0] + bs[0]; o0.y = p[1] + bs[1];
            o0.z = p[2] + bs[2]; o0.w = p[3] + bs[3];
            o1.x = p[4] + bs[4]; o1.y = p[5] + bs[5];
            o1.z = p[6] + bs[6]; o1.w = p[7] + bs[7];
            float4* dst = (float4*)(P + (size_t)r * UU + g * 8);
            dst[0] = o0; dst[1] = o1;
        }

        #pragma unroll
        for (int kk = 0; kk < 16; ++kk) xA[kk] = xB[kk];
    }
}

// ---------------------------------------------------------------------------
// Kernel B (round-6 verbatim — best known: 75 us):
// h_t = tanh(x_t + h_{t-1} @ Wh); fused heads + sigmoid.
// One batch row per 64-lane wave; x-stream (64 KB) staged in LDS upfront
// via gathered global_load_lds width=16. Scan loop: zero global accesses,
// interleaved readlane/FMA, fast tanh.
// ---------------------------------------------------------------------------
__global__ __launch_bounds__(64) void scan_heads(
    const int* __restrict__ tokens, const float* __restrict__ P,
    const float* __restrict__ Wh,
    const float* __restrict__ W1, const float* __restrict__ b1,
    const float* __restrict__ W2, const float* __restrict__ b2,
    float* __restrict__ out)
{
    __shared__ float xs[TT * UU];      // 512 rows x 128 B = 64 KB

    const int L = threadIdx.x;
    const int u = L & 31;
    const int b = blockIdx.x;
    const int* trow = tokens + b * TT;

    // wh[k] = Wh[k][u] : this lane's column of the recurrent matrix
    float wh[UU];
    #pragma unroll
    for (int k = 0; k < UU; ++k) wh[k] = Wh[k * UU + u];

    // ---- gather phase: 64 global_load_lds instrs, 8 tokens each ----
    const int sub = L >> 3;            // token-within-group
    const int q   = L & 7;             // 16-B chunk within the 128-B row
    for (int c = 0; c < 8; ++c) {
        int tk8[8];
        #pragma unroll
        for (int i = 0; i < 8; ++i)
            tk8[i] = trow[c * 64 + i * 8 + sub];
        #pragma unroll
        for (int i = 0; i < 8; ++i) {
            const float* src = P + (size_t)tk8[i] * UU + q * 4;
            float* dst = xs + (c * 64 + i * 8) * UU;    // wave-uniform base
            __builtin_amdgcn_global_load_lds(
                (const __attribute__((address_space(1))) void*)src,
                (__attribute__((address_space(3))) void*)dst, 16, 0, 0);
        }
    }
    __syncthreads();   // drains vmcnt: all LDS rows resident

    // ---- scan: pure LDS + VALU ----
    float xr[4];
    #pragma unroll
    for (int j = 0; j < 4; ++j) xr[j] = xs[j * UU + u];

    float h = 0.f;

    for (int t = 0; t < TT; t += 4) {
        #pragma unroll
        for (int j = 0; j < 4; ++j) {
            float xn = xs[((t + 4 + j) & (TT - 1)) * UU + u];  // prefetch

            float a0 = xr[j], a1 = 0.f, a2 = 0.f, a3 = 0.f;
            #pragma unroll
            for (int k = 0; k < UU; k += 4) {
                float h0 = rdlane(h, k);
                float h1 = rdlane(h, k + 1);
                float h2 = rdlane(h, k + 2);
                float h3 = rdlane(h, k + 3);
                a0 = fmaf(h0, wh[k],     a0);
                a1 = fmaf(h1, wh[k + 1], a1);
                a2 = fmaf(h2, wh[k + 2], a2);
                a3 = fmaf(h3, wh[k + 3], a3);
            }
            h = fast_tanh((a0 + a1) + (a2 + a3));
            xr[j] = xn;
        }
    }

    // ---- fused heads (once; readlane-only) ----
    const int j = threadIdx.x & 15;
    float s = b1[j];
    #pragma unroll
    for (int k = 0; k < UU; ++k) {
        float hk = rdlane(h, k);
        s = fmaf(hk, W1[k * FF1 + j], s);
    }
    float z = b2[0];
    #pragma unroll
    for (int jj = 0; jj < FF1; ++jj) {
        float yj = rdlane(s, jj);
        z = fmaf(yj, W2[jj], z);
    }
    if (threadIdx.x == 0) {
        float e = __builtin_amdgcn_exp2f(-z * 1.4426950408889634f); // e^{-z}
        out[b] = __builtin_amdgcn_rcpf(1.0f + e);
    }
}

// ---------------------------------------------------------------------------
extern "C" void kernel_launch(void* const* d_in, const int* in_sizes, int n_in,
                              void* d_out, int out_size, void* d_ws, size_t ws_size,
                              hipStream_t stream) {
    const int*   tokens = (const int*)  d_in[0];
    const float* emb    = (const float*)d_in[1];
    const float* Wx     = (const float*)d_in[2];
    const float* Wh     = (const float*)d_in[3];
    const float* bias   = (const float*)d_in[4];
    const float* W1     = (const float*)d_in[5];
    const float* b1     = (const float*)d_in[6];
    const float* W2     = (const float*)d_in[7];
    const float* b2     = (const float*)d_in[8];
    float* out = (float*)d_out;

    const int vocab = in_sizes[1] / EE;        // 50000
    float* P = (float*)d_ws;                   // vocab*32*4 = 6.4 MB

    // A: 2048 single-wave blocks, ~25 rows each (8 waves/CU)
    proj_dpp<<<dim3(NWAVE), dim3(64), 0, stream>>>(
        emb, Wx, bias, P, vocab);

    // B: 1 batch row per wave -> 512 blocks x 64 threads (2 blocks/CU)
    scan_heads<<<dim3(BB), dim3(64), 0, stream>>>(
        tokens, P, Wh, W1, b1, W2, b2, out);
}